// Round 14
// baseline (280.564 us; speedup 1.0000x reference)
//
#include <hip/hip_runtime.h>
#include <hip/hip_bf16.h>

typedef float          f4  __attribute__((ext_vector_type(4)));
typedef unsigned short us4 __attribute__((ext_vector_type(4)));
typedef int            i2  __attribute__((ext_vector_type(2)));

template <typename T>
__device__ __forceinline__ T ntload(const T* p) { return __builtin_nontemporal_load(p); }

__device__ __forceinline__ unsigned short f2bf(float f) {
    unsigned u = __float_as_uint(f);
    return (unsigned short)((u + 0x7FFF + ((u >> 16) & 1)) >> 16);   // RNE
}
__device__ __forceinline__ float bf2f(unsigned short h) {
    return __uint_as_float((unsigned)h << 16);
}

// ---- FAT kernel A: blocks [0,2048): degree histogram; [2048,2560): xw GEMM --
// deg: packed = (count << 40) | fixed24(weight-sum); replica = blockIdx & 7
__global__ __launch_bounds__(256) void k_degxw(const int* __restrict__ ei,
                      const float* __restrict__ ew,
                      unsigned long long* __restrict__ deg_rep,
                      const float* __restrict__ x, const float* __restrict__ W1,
                      unsigned short* __restrict__ xw16,
                      int N, int E) {
    __shared__ float w1l[128 * 64];   // 32 KB (xw branch)
    __shared__ f4    xt[16][32];      // 8 KB
    if (blockIdx.x < 2048) {
        int e = blockIdx.x * 256 + threadIdx.x;
        if (e < E) {
            int c = ntload(ei + E + e);
            float w = ntload(ew + e);
            unsigned q = (unsigned)__float2uint_rn(w * 16777216.f);   // 2^24 fixed point
            unsigned long long p = (1ULL << 40) | (unsigned long long)q;
            atomicAdd(&deg_rep[(size_t)(blockIdx.x & 7) * N + c], p);
        }
        return;
    }
    int xbid = blockIdx.x - 2048;     // 512 xw blocks
    for (int t = threadIdx.x; t < 128 * 64; t += 256) w1l[t] = W1[t];
    int lane = threadIdx.x & 63;
    int wv   = threadIdx.x >> 6;
    for (int base = xbid * 16; base < N; base += 512 * 16) {
        __syncthreads();   // also covers w1l staging on first pass
        for (int t = threadIdx.x; t < 16 * 32; t += 256)
            ((f4*)xt)[t] = ntload((const f4*)x + (size_t)base * 32 + t);
        __syncthreads();
        int r0 = wv * 4;
        float a0 = 0.f, a1 = 0.f, a2 = 0.f, a3 = 0.f;
#pragma unroll
        for (int q = 0; q < 32; ++q) {
            f4 x0 = xt[r0][q], x1 = xt[r0 + 1][q], x2 = xt[r0 + 2][q], x3 = xt[r0 + 3][q];
            float wa = w1l[(4 * q + 0) * 64 + lane];
            float wb = w1l[(4 * q + 1) * 64 + lane];
            float wc = w1l[(4 * q + 2) * 64 + lane];
            float wd = w1l[(4 * q + 3) * 64 + lane];
            a0 = fmaf(x0.x, wa, a0); a0 = fmaf(x0.y, wb, a0); a0 = fmaf(x0.z, wc, a0); a0 = fmaf(x0.w, wd, a0);
            a1 = fmaf(x1.x, wa, a1); a1 = fmaf(x1.y, wb, a1); a1 = fmaf(x1.z, wc, a1); a1 = fmaf(x1.w, wd, a1);
            a2 = fmaf(x2.x, wa, a2); a2 = fmaf(x2.y, wb, a2); a2 = fmaf(x2.z, wc, a2); a2 = fmaf(x2.w, wd, a2);
            a3 = fmaf(x3.x, wa, a3); a3 = fmaf(x3.y, wb, a3); a3 = fmaf(x3.z, wc, a3); a3 = fmaf(x3.w, wd, a3);
        }
        int gr = base + r0;
        xw16[(size_t)(gr + 0) * 64 + lane] = f2bf(a0);
        xw16[(size_t)(gr + 1) * 64 + lane] = f2bf(a1);
        xw16[(size_t)(gr + 2) * 64 + lane] = f2bf(a2);
        xw16[(size_t)(gr + 3) * 64 + lane] = f2bf(a3);
    }
}

// ---- reduce replicas: cnt[c], dis[c]=rsqrt(deg+1), per-replica offsets ------
__global__ void k_red(const unsigned long long* __restrict__ deg_rep,
                      int* __restrict__ off_rep, int* __restrict__ cnt,
                      float* __restrict__ dis, int N) {
    int c = blockIdx.x * blockDim.x + threadIdx.x;
    if (c >= N) return;
    int run = 0;
    unsigned long long wsum = 0;
#pragma unroll
    for (int rep = 0; rep < 8; ++rep) {
        unsigned long long p = deg_rep[(size_t)rep * N + c];
        off_rep[(size_t)rep * N + c] = run;
        run += (int)(p >> 40);
        wsum += (p & ((1ULL << 40) - 1));
    }
    cnt[c] = run;
    dis[c] = rsqrtf((float)wsum * (1.f / 16777216.f) + 1.0f);
}

// ---- exclusive prefix sum of cnt -> offs[0..N] ------------------------------
__global__ void k_scan(const int* __restrict__ cnt, int* __restrict__ offs, int N) {
    __shared__ int part[1024];
    int tid = threadIdx.x;
    int C = (N + 1023) / 1024;   // 16 for N=16384
    int base = tid * C;
    int loc[16];
    int sum = 0;
#pragma unroll
    for (int i = 0; i < 16; ++i) {
        if (i < C) {
            int idx = base + i;
            loc[i] = sum;
            sum += (idx < N) ? cnt[idx] : 0;
        }
    }
    part[tid] = sum;
    __syncthreads();
    for (int o = 1; o < 1024; o <<= 1) {
        int t = (tid >= o) ? part[tid - o] : 0;
        __syncthreads();
        part[tid] += t;
        __syncthreads();
    }
    int excl = part[tid] - sum;
#pragma unroll
    for (int i = 0; i < 16; ++i) {
        if (i < C) {
            int idx = base + i;
            if (idx < N) offs[idx] = excl + loc[i];
        }
    }
    if (tid == 1023) offs[N] = part[tid];
}

// ---- counting-sort edges into buckets, replicated cursors, packed record ----
__global__ void k_bucket(const int* __restrict__ ei, const float* __restrict__ ew,
                         const float* __restrict__ dis, const int* __restrict__ offs,
                         const int* __restrict__ off_rep, int* __restrict__ cursor_rep,
                         i2* __restrict__ barr, int N, int E) {
    int e = blockIdx.x * blockDim.x + threadIdx.x;
    if (e < E) {
        int rep = blockIdx.x & 7;
        int r = ntload(ei + e), c = ntload(ei + E + e);
        float norm = dis[r] * ntload(ew + e) * dis[c];
        size_t rc = (size_t)rep * N + c;
        int pos = offs[c] + off_rep[rc] + atomicAdd(&cursor_rep[rc], 1);
        i2 rec; rec.x = r; rec.y = __float_as_int(norm);
        __builtin_nontemporal_store(rec, barr + pos);
    }
}

// ---- FUSED gather + MLP + softmax: row-pairs, writes s (f32) and s16 --------
// h row stays in registers (replicated across subs); MLP via shfl broadcasts.
__global__ __launch_bounds__(256) void k_gathmlp(const int* __restrict__ offs,
                         const i2* __restrict__ barr,
                         const unsigned short* __restrict__ xw16,
                         const float* __restrict__ dis, const float* __restrict__ b1,
                         const float* __restrict__ Wm1, const float* __restrict__ bm1,
                         const float* __restrict__ Wm2, const float* __restrict__ bm2,
                         float* __restrict__ s, unsigned short* __restrict__ s16, int N) {
    __shared__ unsigned short w1l[4096], w2l[4096];   // 16 KB bf16 weights
    __shared__ float b1m[64], b2m[64];
    for (int t = threadIdx.x; t < 4096; t += 256) {
        w1l[t] = f2bf(Wm1[t]);
        w2l[t] = f2bf(Wm2[t]);
    }
    if (threadIdx.x < 64) {
        b1m[threadIdx.x] = bm1[threadIdx.x];
        b2m[threadIdx.x] = bm2[threadIdx.x];
    }
    __syncthreads();
    int lane = threadIdx.x & 63;
    int sub = lane >> 4, q = lane & 15;
    int wid  = blockIdx.x * 4 + (threadIdx.x >> 6);
    int nw   = 4 * gridDim.x;
    const us4* xw16v = (const us4*)xw16;
    for (int cp = wid; cp < (N >> 1); cp += nw) {
        int c0 = 2 * cp, c1 = c0 + 1;
        int beg = ntload(offs + c0), mid = ntload(offs + c1), end = ntload(offs + c1 + 1);
        f4 A0 = {0.f, 0.f, 0.f, 0.f}, A1 = A0, B0 = A0, B1 = A0;
        for (int i = beg; i < end; i += 64) {
            int nloc = min(64, end - i);
            bool ok = (i + lane < end);
            i2 b = ok ? ntload(barr + i + lane) : (i2){0, 0};
            int   rv = b.x;
            float nv = __int_as_float(b.y);   // padded lanes: norm = 0
            int jmax = (nloc + 3) >> 2;
            int j = 0;
            for (; j + 4 <= jmax; j += 4) {   // 16 edges: 4 independent load chains
                int e0 = 4 * j + sub;
                int g0 = i + e0;
                int   r0 = __shfl(rv, e0),      r1 = __shfl(rv, e0 + 4);
                int   r2 = __shfl(rv, e0 + 8),  r3 = __shfl(rv, e0 + 12);
                float n0 = __shfl(nv, e0),      n1 = __shfl(nv, e0 + 4);
                float n2 = __shfl(nv, e0 + 8),  n3 = __shfl(nv, e0 + 12);
                us4 u0 = xw16v[(size_t)r0 * 16 + q];
                us4 u1 = xw16v[(size_t)r1 * 16 + q];
                us4 u2 = xw16v[(size_t)r2 * 16 + q];
                us4 u3 = xw16v[(size_t)r3 * 16 + q];
                float a0w = (g0      < mid) ? n0 : 0.f, b0w = n0 - a0w;
                float a1w = (g0 + 4  < mid) ? n1 : 0.f, b1w = n1 - a1w;
                float a2w = (g0 + 8  < mid) ? n2 : 0.f, b2w = n2 - a2w;
                float a3w = (g0 + 12 < mid) ? n3 : 0.f, b3w = n3 - a3w;
                A0.x = fmaf(bf2f(u0.x), a0w, A0.x); A0.y = fmaf(bf2f(u0.y), a0w, A0.y);
                A0.z = fmaf(bf2f(u0.z), a0w, A0.z); A0.w = fmaf(bf2f(u0.w), a0w, A0.w);
                B0.x = fmaf(bf2f(u0.x), b0w, B0.x); B0.y = fmaf(bf2f(u0.y), b0w, B0.y);
                B0.z = fmaf(bf2f(u0.z), b0w, B0.z); B0.w = fmaf(bf2f(u0.w), b0w, B0.w);
                A1.x = fmaf(bf2f(u1.x), a1w, A1.x); A1.y = fmaf(bf2f(u1.y), a1w, A1.y);
                A1.z = fmaf(bf2f(u1.z), a1w, A1.z); A1.w = fmaf(bf2f(u1.w), a1w, A1.w);
                B1.x = fmaf(bf2f(u1.x), b1w, B1.x); B1.y = fmaf(bf2f(u1.y), b1w, B1.y);
                B1.z = fmaf(bf2f(u1.z), b1w, B1.z); B1.w = fmaf(bf2f(u1.w), b1w, B1.w);
                A0.x = fmaf(bf2f(u2.x), a2w, A0.x); A0.y = fmaf(bf2f(u2.y), a2w, A0.y);
                A0.z = fmaf(bf2f(u2.z), a2w, A0.z); A0.w = fmaf(bf2f(u2.w), a2w, A0.w);
                B0.x = fmaf(bf2f(u2.x), b2w, B0.x); B0.y = fmaf(bf2f(u2.y), b2w, B0.y);
                B0.z = fmaf(bf2f(u2.z), b2w, B0.z); B0.w = fmaf(bf2f(u2.w), b2w, B0.w);
                A1.x = fmaf(bf2f(u3.x), a3w, A1.x); A1.y = fmaf(bf2f(u3.y), a3w, A1.y);
                A1.z = fmaf(bf2f(u3.z), a3w, A1.z); A1.w = fmaf(bf2f(u3.w), a3w, A1.w);
                B1.x = fmaf(bf2f(u3.x), b3w, B1.x); B1.y = fmaf(bf2f(u3.y), b3w, B1.y);
                B1.z = fmaf(bf2f(u3.z), b3w, B1.z); B1.w = fmaf(bf2f(u3.w), b3w, B1.w);
            }
            for (; j < jmax; ++j) {
                int e = 4 * j + sub;
                int g = i + e;
                int   r  = __shfl(rv, e);
                float nm = __shfl(nv, e);
                us4 u = xw16v[(size_t)r * 16 + q];
                float aw = (g < mid) ? nm : 0.f, bw = nm - aw;
                A0.x = fmaf(bf2f(u.x), aw, A0.x); A0.y = fmaf(bf2f(u.y), aw, A0.y);
                A0.z = fmaf(bf2f(u.z), aw, A0.z); A0.w = fmaf(bf2f(u.w), aw, A0.w);
                B0.x = fmaf(bf2f(u.x), bw, B0.x); B0.y = fmaf(bf2f(u.y), bw, B0.y);
                B0.z = fmaf(bf2f(u.z), bw, B0.z); B0.w = fmaf(bf2f(u.w), bw, B0.w);
            }
        }
        A0.x += A1.x; A0.y += A1.y; A0.z += A1.z; A0.w += A1.w;
        B0.x += B1.x; B0.y += B1.y; B0.z += B1.z; B0.w += B1.w;
        A0.x += __shfl_xor(A0.x, 16); A0.y += __shfl_xor(A0.y, 16);
        A0.z += __shfl_xor(A0.z, 16); A0.w += __shfl_xor(A0.w, 16);
        B0.x += __shfl_xor(B0.x, 16); B0.y += __shfl_xor(B0.y, 16);
        B0.z += __shfl_xor(B0.z, 16); B0.w += __shfl_xor(B0.w, 16);
        A0.x += __shfl_xor(A0.x, 32); A0.y += __shfl_xor(A0.y, 32);
        A0.z += __shfl_xor(A0.z, 32); A0.w += __shfl_xor(A0.w, 32);
        B0.x += __shfl_xor(B0.x, 32); B0.y += __shfl_xor(B0.y, 32);
        B0.z += __shfl_xor(B0.z, 32); B0.w += __shfl_xor(B0.w, 32);
        // h rows (relu'd); every lane holds h[4q..4q+3], replicated across subs
        f4 bb = ((const f4*)b1)[q];
        us4 su0 = xw16v[(size_t)c0 * 16 + q];
        us4 su1 = xw16v[(size_t)c1 * 16 + q];
        float d0 = dis[c0], d1 = dis[c1];
        float dd0 = d0 * d0, dd1 = d1 * d1;
        f4 v0, v1;
        v0.x = A0.x + bf2f(su0.x) * dd0 + bb.x; v0.y = A0.y + bf2f(su0.y) * dd0 + bb.y;
        v0.z = A0.z + bf2f(su0.z) * dd0 + bb.z; v0.w = A0.w + bf2f(su0.w) * dd0 + bb.w;
        v1.x = B0.x + bf2f(su1.x) * dd1 + bb.x; v1.y = B0.y + bf2f(su1.y) * dd1 + bb.y;
        v1.z = B0.z + bf2f(su1.z) * dd1 + bb.z; v1.w = B0.w + bf2f(su1.w) * dd1 + bb.w;
        v0.x = v0.x > 0.f ? v0.x : 0.f; v0.y = v0.y > 0.f ? v0.y : 0.f;
        v0.z = v0.z > 0.f ? v0.z : 0.f; v0.w = v0.w > 0.f ? v0.w : 0.f;
        v1.x = v1.x > 0.f ? v1.x : 0.f; v1.y = v1.y > 0.f ? v1.y : 0.f;
        v1.z = v1.z > 0.f ? v1.z : 0.f; v1.w = v1.w > 0.f ? v1.w : 0.f;
        // ---- fused MLP layer 1: t[lane] = bm1[lane] + sum_k h[k]*Wm1[k][lane]
        float tA = b1m[lane], tB = tA;
#pragma unroll
        for (int k4 = 0; k4 < 16; ++k4) {
            float h00 = __shfl(v0.x, k4), h01 = __shfl(v0.y, k4);
            float h02 = __shfl(v0.z, k4), h03 = __shfl(v0.w, k4);
            float h10 = __shfl(v1.x, k4), h11 = __shfl(v1.y, k4);
            float h12 = __shfl(v1.z, k4), h13 = __shfl(v1.w, k4);
            float wa = bf2f(w1l[(4 * k4 + 0) * 64 + lane]);
            float wb = bf2f(w1l[(4 * k4 + 1) * 64 + lane]);
            float wc = bf2f(w1l[(4 * k4 + 2) * 64 + lane]);
            float wd = bf2f(w1l[(4 * k4 + 3) * 64 + lane]);
            tA = fmaf(h00, wa, tA); tA = fmaf(h01, wb, tA);
            tA = fmaf(h02, wc, tA); tA = fmaf(h03, wd, tA);
            tB = fmaf(h10, wa, tB); tB = fmaf(h11, wb, tB);
            tB = fmaf(h12, wc, tB); tB = fmaf(h13, wd, tB);
        }
        // ---- layer 2: g[lane] = bm2[lane] + sum_k t[k]*Wm2[k][lane]
        float gA = b2m[lane], gB = gA;
#pragma unroll
        for (int k4 = 0; k4 < 16; ++k4) {
            float tA0 = __shfl(tA, 4 * k4),     tA1 = __shfl(tA, 4 * k4 + 1);
            float tA2 = __shfl(tA, 4 * k4 + 2), tA3 = __shfl(tA, 4 * k4 + 3);
            float tB0 = __shfl(tB, 4 * k4),     tB1 = __shfl(tB, 4 * k4 + 1);
            float tB2 = __shfl(tB, 4 * k4 + 2), tB3 = __shfl(tB, 4 * k4 + 3);
            float wa = bf2f(w2l[(4 * k4 + 0) * 64 + lane]);
            float wb = bf2f(w2l[(4 * k4 + 1) * 64 + lane]);
            float wc = bf2f(w2l[(4 * k4 + 2) * 64 + lane]);
            float wd = bf2f(w2l[(4 * k4 + 3) * 64 + lane]);
            gA = fmaf(tA0, wa, gA); gA = fmaf(tA1, wb, gA);
            gA = fmaf(tA2, wc, gA); gA = fmaf(tA3, wd, gA);
            gB = fmaf(tB0, wa, gB); gB = fmaf(tB1, wb, gB);
            gB = fmaf(tB2, wc, gB); gB = fmaf(tB3, wd, gB);
        }
        // ---- softmax over 64 lanes, both rows
        float mA = gA, mB = gB;
#pragma unroll
        for (int o = 32; o > 0; o >>= 1) {
            mA = fmaxf(mA, __shfl_xor(mA, o));
            mB = fmaxf(mB, __shfl_xor(mB, o));
        }
        float eA = __expf(gA - mA), eB = __expf(gB - mB);
        float sA = eA, sB = eB;
#pragma unroll
        for (int o = 32; o > 0; o >>= 1) {
            sA += __shfl_xor(sA, o);
            sB += __shfl_xor(sB, o);
        }
        float oA = eA / sA, oB = eB / sB;
        __builtin_nontemporal_store(oA, s + (size_t)c0 * 64 + lane);
        __builtin_nontemporal_store(oB, s + (size_t)c1 * 64 + lane);
        s16[(size_t)c0 * 64 + lane] = f2bf(oA);
        s16[(size_t)c1 * 64 + lane] = f2bf(oB);
    }
}

// ---- FAT kernel B: blocks [0,2048): trace; [2048,2304): row reductions ------
__global__ __launch_bounds__(256) void k_rt(const int* __restrict__ offs,
                         const i2* __restrict__ barr,
                         const unsigned short* __restrict__ s16,
                         const float* __restrict__ s, const int* __restrict__ cnt,
                         float* __restrict__ ssg, float* __restrict__ cag,
                         float* __restrict__ csg, float* __restrict__ tracearr, int N) {
    __shared__ float tile[64][64];   // 16 KB (rowred branch)
    __shared__ float bsum;
    int lane = threadIdx.x & 63;
    int wv   = threadIdx.x >> 6;
    if (blockIdx.x >= 2048) {
        // ---- rowred branch: 256 blocks, one 64-row tile each ----
        int base = (blockIdx.x - 2048) * 64;
        if (base >= N) return;
        for (int t = threadIdx.x; t < 1024; t += 256)
            ((f4*)tile)[t] = ntload((const f4*)(s + (size_t)base * 64) + t);
        __syncthreads();
        float acc[16];
#pragma unroll
        for (int i = 0; i < 16; ++i) acc[i] = 0.f;
        for (int r = 0; r < 64; ++r) {
            float sj = tile[r][lane];
            const float* brow = &tile[r][wv * 16];
#pragma unroll
            for (int i = 0; i < 16; ++i) acc[i] = fmaf(brow[i], sj, acc[i]);
        }
        float csj = 0.f, caj = 0.f;
#pragma unroll
        for (int i = 0; i < 16; ++i) {
            int r = wv * 16 + i;
            float sj = tile[r][lane];
            csj += sj;
            caj = fmaf(sj, (float)cnt[base + r], caj);
        }
#pragma unroll
        for (int i = 0; i < 16; ++i) atomicAdd(&ssg[(wv * 16 + i) * 64 + lane], acc[i]);
        atomicAdd(&csg[lane], csj);
        atomicAdd(&cag[lane], caj);
        return;
    }
    // ---- trace branch: 2048 blocks, row-pairs over contiguous CSR ranges ----
    int sub = lane >> 4, q = lane & 15;
    int wid  = blockIdx.x * 4 + wv;
    int nw   = 4 * 2048;
    const us4* s16v = (const us4*)s16;
    float tacc = 0.f;
    for (int cp = wid; cp < (N >> 1); cp += nw) {
        int c0 = 2 * cp, c1 = c0 + 1;
        int beg = ntload(offs + c0), mid = ntload(offs + c1), end = ntload(offs + c1 + 1);
        us4 scu0 = s16v[(size_t)c0 * 16 + q];
        us4 scu1 = s16v[(size_t)c1 * 16 + q];
        f4 sc0 = {bf2f(scu0.x), bf2f(scu0.y), bf2f(scu0.z), bf2f(scu0.w)};
        f4 sc1 = {bf2f(scu1.x), bf2f(scu1.y), bf2f(scu1.z), bf2f(scu1.w)};
        f4 A0 = {0.f, 0.f, 0.f, 0.f}, A1 = A0, B0 = A0, B1 = A0;
        for (int i = beg; i < end; i += 64) {
            int nloc = min(64, end - i);
            int rv = (i + lane < end) ? ntload(barr + i + lane).x : 0;
            int jmax = (nloc + 3) >> 2;
            int j = 0;
            for (; j + 4 <= jmax; j += 4) {
                int e0 = 4 * j + sub;
                int g0 = i + e0;
                int r0 = __shfl(rv, e0),     r1 = __shfl(rv, e0 + 4);
                int r2 = __shfl(rv, e0 + 8), r3 = __shfl(rv, e0 + 12);
                float n0 = (e0      < nloc) ? 1.f : 0.f;
                float n1 = (e0 + 4  < nloc) ? 1.f : 0.f;
                float n2 = (e0 + 8  < nloc) ? 1.f : 0.f;
                float n3 = (e0 + 12 < nloc) ? 1.f : 0.f;
                us4 u0 = s16v[(size_t)r0 * 16 + q];
                us4 u1 = s16v[(size_t)r1 * 16 + q];
                us4 u2 = s16v[(size_t)r2 * 16 + q];
                us4 u3 = s16v[(size_t)r3 * 16 + q];
                float a0w = (g0      < mid) ? n0 : 0.f, b0w = n0 - a0w;
                float a1w = (g0 + 4  < mid) ? n1 : 0.f, b1w = n1 - a1w;
                float a2w = (g0 + 8  < mid) ? n2 : 0.f, b2w = n2 - a2w;
                float a3w = (g0 + 12 < mid) ? n3 : 0.f, b3w = n3 - a3w;
                A0.x = fmaf(bf2f(u0.x), a0w, A0.x); A0.y = fmaf(bf2f(u0.y), a0w, A0.y);
                A0.z = fmaf(bf2f(u0.z), a0w, A0.z); A0.w = fmaf(bf2f(u0.w), a0w, A0.w);
                B0.x = fmaf(bf2f(u0.x), b0w, B0.x); B0.y = fmaf(bf2f(u0.y), b0w, B0.y);
                B0.z = fmaf(bf2f(u0.z), b0w, B0.z); B0.w = fmaf(bf2f(u0.w), b0w, B0.w);
                A1.x = fmaf(bf2f(u1.x), a1w, A1.x); A1.y = fmaf(bf2f(u1.y), a1w, A1.y);
                A1.z = fmaf(bf2f(u1.z), a1w, A1.z); A1.w = fmaf(bf2f(u1.w), a1w, A1.w);
                B1.x = fmaf(bf2f(u1.x), b1w, B1.x); B1.y = fmaf(bf2f(u1.y), b1w, B1.y);
                B1.z = fmaf(bf2f(u1.z), b1w, B1.z); B1.w = fmaf(bf2f(u1.w), b1w, B1.w);
                A0.x = fmaf(bf2f(u2.x), a2w, A0.x); A0.y = fmaf(bf2f(u2.y), a2w, A0.y);
                A0.z = fmaf(bf2f(u2.z), a2w, A0.z); A0.w = fmaf(bf2f(u2.w), a2w, A0.w);
                B0.x = fmaf(bf2f(u2.x), b2w, B0.x); B0.y = fmaf(bf2f(u2.y), b2w, B0.y);
                B0.z = fmaf(bf2f(u2.z), b2w, B0.z); B0.w = fmaf(bf2f(u2.w), b2w, B0.w);
                A1.x = fmaf(bf2f(u3.x), a3w, A1.x); A1.y = fmaf(bf2f(u3.y), a3w, A1.y);
                A1.z = fmaf(bf2f(u3.z), a3w, A1.z); A1.w = fmaf(bf2f(u3.w), a3w, A1.w);
                B1.x = fmaf(bf2f(u3.x), b3w, B1.x); B1.y = fmaf(bf2f(u3.y), b3w, B1.y);
                B1.z = fmaf(bf2f(u3.z), b3w, B1.z); B1.w = fmaf(bf2f(u3.w), b3w, B1.w);
            }
            for (; j < jmax; ++j) {
                int e = 4 * j + sub;
                int g = i + e;
                int r = __shfl(rv, e);
                float m = (e < nloc) ? 1.f : 0.f;
                us4 u = s16v[(size_t)r * 16 + q];
                float aw = (g < mid) ? m : 0.f, bw = m - aw;
                A0.x = fmaf(bf2f(u.x), aw, A0.x); A0.y = fmaf(bf2f(u.y), aw, A0.y);
                A0.z = fmaf(bf2f(u.z), aw, A0.z); A0.w = fmaf(bf2f(u.w), aw, A0.w);
                B0.x = fmaf(bf2f(u.x), bw, B0.x); B0.y = fmaf(bf2f(u.y), bw, B0.y);
                B0.z = fmaf(bf2f(u.z), bw, B0.z); B0.w = fmaf(bf2f(u.w), bw, B0.w);
            }
        }
        A0.x += A1.x; A0.y += A1.y; A0.z += A1.z; A0.w += A1.w;
        B0.x += B1.x; B0.y += B1.y; B0.z += B1.z; B0.w += B1.w;
        A0.x += __shfl_xor(A0.x, 16); A0.y += __shfl_xor(A0.y, 16);
        A0.z += __shfl_xor(A0.z, 16); A0.w += __shfl_xor(A0.w, 16);
        B0.x += __shfl_xor(B0.x, 16); B0.y += __shfl_xor(B0.y, 16);
        B0.z += __shfl_xor(B0.z, 16); B0.w += __shfl_xor(B0.w, 16);
        A0.x += __shfl_xor(A0.x, 32); A0.y += __shfl_xor(A0.y, 32);
        A0.z += __shfl_xor(A0.z, 32); A0.w += __shfl_xor(A0.w, 32);
        B0.x += __shfl_xor(B0.x, 32); B0.y += __shfl_xor(B0.y, 32);
        B0.z += __shfl_xor(B0.z, 32); B0.w += __shfl_xor(B0.w, 32);
        tacc += A0.x * sc0.x + A0.y * sc0.y + A0.z * sc0.z + A0.w * sc0.w;
        tacc += B0.x * sc1.x + B0.y * sc1.y + B0.z * sc1.z + B0.w * sc1.w;
    }
    tacc *= 0.25f;   // each q-partial replicated across 4 subs
#pragma unroll
    for (int o = 32; o > 0; o >>= 1) tacc += __shfl_xor(tacc, o);
    if (threadIdx.x == 0) bsum = 0.f;
    __syncthreads();
    if (lane == 0) atomicAdd(&bsum, tacc);
    __syncthreads();
    if (threadIdx.x == 0) tracearr[blockIdx.x] = bsum;   // per-block partial
}

// ---- finalize: spectral + ortho + cluster loss ------------------------------
__global__ void k_final(const float* __restrict__ ssg, const float* __restrict__ cag,
                        const float* __restrict__ csg, const float* __restrict__ tracearr,
                        int ntr, float Ef, float Nf, float* __restrict__ out) {
    __shared__ float red[256];
    int tid = threadIdx.x;

    float a = 0.f;
    for (int t = tid; t < ntr; t += 256) a += tracearr[t];
    red[tid] = a; __syncthreads();
    for (int o = 128; o > 0; o >>= 1) { if (tid < o) red[tid] += red[tid + o]; __syncthreads(); }
    float trace = red[0]; __syncthreads();

    a = 0.f;
    for (int t = tid; t < 4096; t += 256) { float v = ssg[t]; a += v * v; }
    red[tid] = a; __syncthreads();
    for (int o = 128; o > 0; o >>= 1) { if (tid < o) red[tid] += red[tid + o]; __syncthreads(); }
    float ss_sumsq = red[0]; __syncthreads();

    a = (tid < 64) ? ssg[tid * 64 + tid] : 0.f;
    red[tid] = a; __syncthreads();
    for (int o = 128; o > 0; o >>= 1) { if (tid < o) red[tid] += red[tid + o]; __syncthreads(); }
    float tr_ss = red[0]; __syncthreads();

    a = (tid < 64) ? cag[tid] * cag[tid] : 0.f;
    red[tid] = a; __syncthreads();
    for (int o = 128; o > 0; o >>= 1) { if (tid < o) red[tid] += red[tid + o]; __syncthreads(); }
    float ca_ss = red[0]; __syncthreads();

    a = (tid < 64) ? csg[tid] * csg[tid] : 0.f;
    red[tid] = a; __syncthreads();
    for (int o = 128; o > 0; o >>= 1) { if (tid < o) red[tid] += red[tid + o]; __syncthreads(); }
    float cs_ss = red[0];

    if (tid == 0) {
        // 2m = deg.sum() = E
        float spec = -(trace - ca_ss / Ef) / Ef;
        float ss_fro = sqrtf(ss_sumsq);
        // ||ss/fro - I/8||_F^2 = 1 - tr(ss)/(4*fro) + 1
        float ortho = sqrtf(fmaxf(2.f - tr_ss / (4.f * ss_fro), 0.f));
        float clus = sqrtf(cs_ss) / Nf * 8.f - 1.f;
        out[0] = spec + ortho + clus;
    }
}

extern "C" void kernel_launch(void* const* d_in, const int* in_sizes, int n_in,
                              void* d_out, int out_size, void* d_ws, size_t ws_size,
                              hipStream_t stream) {
    const float* x   = (const float*)d_in[0];
    const int*   ei  = (const int*)d_in[1];
    const float* ew  = (const float*)d_in[2];
    const float* W1  = (const float*)d_in[3];
    const float* b1  = (const float*)d_in[4];
    const float* Wm1 = (const float*)d_in[5];
    const float* bm1 = (const float*)d_in[6];
    const float* Wm2 = (const float*)d_in[7];
    const float* bm2 = (const float*)d_in[8];
    float* out = (float*)d_out;

    const int N = in_sizes[0] / 128;   // 16384
    const int E = in_sizes[2];         // 524288
    const int TGRID = 2304;            // fat kernel B grid (2048 trace + 256 rowred)

    char* base = (char*)d_ws;
    // --- zeroed region (atomics accumulate) ---
    unsigned long long* deg_rep = (unsigned long long*)base;        // 8N u64 (1 MB)
    int*   cursor_rep = (int*)(base + (size_t)64 * N);              // 8N int (512 KB)
    float* ssg = (float*)(base + (size_t)96 * N);                   // 4096 f
    float* cag = ssg + 4096;                                        // 64
    float* csg = cag + 64;                                          // 64
    size_t zbytes = (size_t)96 * N + (4096 + 128) * 4;
    // --- uninitialized region ---
    char* up = base + ((zbytes + 15) & ~(size_t)15);
    int*   cnt = (int*)up;            up += (size_t)4 * N;
    float* dis = (float*)up;          up += (size_t)4 * N;
    int*   offs = (int*)up;           up += (size_t)4 * (N + 1);
    float* tracearr = (float*)up;     up += (size_t)4 * TGRID;
    up = (char*)(((size_t)up + 15) & ~(size_t)15);
    int*   off_rep = (int*)up;        up += (size_t)32 * N;         // 8N int (512 KB)
    i2*    barr = (i2*)up;            up += (size_t)8 * E;          // 4 MB
    unsigned short* xw16 = (unsigned short*)up; up += (size_t)2 * N * 64;  // 2 MB
    unsigned short* s16  = (unsigned short*)up;                            // 2 MB
    float* sbuf = out;                // s lives in d_out (f32 output 0)

    hipMemsetAsync(d_ws, 0, zbytes, stream);

    k_degxw<<<2560, 256, 0, stream>>>(ei, ew, deg_rep, x, W1, xw16, N, E);
    k_red<<<(N + 255) / 256, 256, 0, stream>>>(deg_rep, off_rep, cnt, dis, N);
    k_scan<<<1, 1024, 0, stream>>>(cnt, offs, N);
    k_bucket<<<(E + 255) / 256, 256, 0, stream>>>(ei, ew, dis, offs, off_rep, cursor_rep, barr, N, E);
    k_gathmlp<<<2048, 256, 0, stream>>>(offs, barr, xw16, dis, b1, Wm1, bm1, Wm2, bm2,
                                        sbuf, s16, N);
    k_rt<<<TGRID, 256, 0, stream>>>(offs, barr, s16, sbuf, cnt, ssg, cag, csg, tracearr, N);
    k_final<<<1, 256, 0, stream>>>(ssg, cag, csg, tracearr, TGRID, (float)E, (float)N,
                                   out + (size_t)N * 64);
}

// Round 15
// 234.346 us; speedup vs baseline: 1.1972x; 1.1972x over previous
//
#include <hip/hip_runtime.h>
#include <hip/hip_bf16.h>

typedef float          f4  __attribute__((ext_vector_type(4)));
typedef unsigned short us4 __attribute__((ext_vector_type(4)));
typedef int            i2  __attribute__((ext_vector_type(2)));

template <typename T>
__device__ __forceinline__ T ntload(const T* p) { return __builtin_nontemporal_load(p); }

__device__ __forceinline__ unsigned short f2bf(float f) {
    unsigned u = __float_as_uint(f);
    return (unsigned short)((u + 0x7FFF + ((u >> 16) & 1)) >> 16);   // RNE
}
__device__ __forceinline__ float bf2f(unsigned short h) {
    return __uint_as_float((unsigned)h << 16);
}

// ---- FAT kernel A: blocks [0,2048): degree histogram; [2048,2560): xw GEMM --
// deg: packed = (count << 40) | fixed24(weight-sum); replica = blockIdx & 7
// (edge e lives in block e>>8 -> same rep mapping as k_bucket's grid)
__global__ __launch_bounds__(256) void k_degxw(const int* __restrict__ ei,
                      const float* __restrict__ ew,
                      unsigned long long* __restrict__ deg_rep,
                      const float* __restrict__ x, const float* __restrict__ W1,
                      float* __restrict__ xw, unsigned short* __restrict__ xw16,
                      int N, int E) {
    __shared__ float w1l[128 * 64];   // 32 KB (xw branch)
    __shared__ f4    xt[16][32];      // 8 KB
    if (blockIdx.x < 2048) {
        int e = blockIdx.x * 256 + threadIdx.x;
        if (e < E) {
            int c = ntload(ei + E + e);
            float w = ntload(ew + e);
            unsigned q = (unsigned)__float2uint_rn(w * 16777216.f);   // 2^24 fixed point
            unsigned long long p = (1ULL << 40) | (unsigned long long)q;
            atomicAdd(&deg_rep[(size_t)(blockIdx.x & 7) * N + c], p);
        }
        return;
    }
    int xbid = blockIdx.x - 2048;     // 512 xw blocks
    for (int t = threadIdx.x; t < 128 * 64; t += 256) w1l[t] = W1[t];
    int lane = threadIdx.x & 63;
    int wv   = threadIdx.x >> 6;
    for (int base = xbid * 16; base < N; base += 512 * 16) {
        __syncthreads();   // also covers w1l staging on first pass
        for (int t = threadIdx.x; t < 16 * 32; t += 256)
            ((f4*)xt)[t] = ntload((const f4*)x + (size_t)base * 32 + t);
        __syncthreads();
        int r0 = wv * 4;
        float a0 = 0.f, a1 = 0.f, a2 = 0.f, a3 = 0.f;
#pragma unroll
        for (int q = 0; q < 32; ++q) {
            f4 x0 = xt[r0][q], x1 = xt[r0 + 1][q], x2 = xt[r0 + 2][q], x3 = xt[r0 + 3][q];
            float wa = w1l[(4 * q + 0) * 64 + lane];
            float wb = w1l[(4 * q + 1) * 64 + lane];
            float wc = w1l[(4 * q + 2) * 64 + lane];
            float wd = w1l[(4 * q + 3) * 64 + lane];
            a0 = fmaf(x0.x, wa, a0); a0 = fmaf(x0.y, wb, a0); a0 = fmaf(x0.z, wc, a0); a0 = fmaf(x0.w, wd, a0);
            a1 = fmaf(x1.x, wa, a1); a1 = fmaf(x1.y, wb, a1); a1 = fmaf(x1.z, wc, a1); a1 = fmaf(x1.w, wd, a1);
            a2 = fmaf(x2.x, wa, a2); a2 = fmaf(x2.y, wb, a2); a2 = fmaf(x2.z, wc, a2); a2 = fmaf(x2.w, wd, a2);
            a3 = fmaf(x3.x, wa, a3); a3 = fmaf(x3.y, wb, a3); a3 = fmaf(x3.z, wc, a3); a3 = fmaf(x3.w, wd, a3);
        }
        int gr = base + r0;
        __builtin_nontemporal_store(a0, xw + (size_t)(gr + 0) * 64 + lane);
        __builtin_nontemporal_store(a1, xw + (size_t)(gr + 1) * 64 + lane);
        __builtin_nontemporal_store(a2, xw + (size_t)(gr + 2) * 64 + lane);
        __builtin_nontemporal_store(a3, xw + (size_t)(gr + 3) * 64 + lane);
        xw16[(size_t)(gr + 0) * 64 + lane] = f2bf(a0);
        xw16[(size_t)(gr + 1) * 64 + lane] = f2bf(a1);
        xw16[(size_t)(gr + 2) * 64 + lane] = f2bf(a2);
        xw16[(size_t)(gr + 3) * 64 + lane] = f2bf(a3);
    }
}

// ---- reduce replicas: cnt[c], dis[c]=rsqrt(deg+1), per-replica offsets ------
__global__ void k_red(const unsigned long long* __restrict__ deg_rep,
                      int* __restrict__ off_rep, int* __restrict__ cnt,
                      float* __restrict__ dis, int N) {
    int c = blockIdx.x * blockDim.x + threadIdx.x;
    if (c >= N) return;
    int run = 0;
    unsigned long long wsum = 0;
#pragma unroll
    for (int rep = 0; rep < 8; ++rep) {
        unsigned long long p = deg_rep[(size_t)rep * N + c];
        off_rep[(size_t)rep * N + c] = run;
        run += (int)(p >> 40);
        wsum += (p & ((1ULL << 40) - 1));
    }
    cnt[c] = run;
    dis[c] = rsqrtf((float)wsum * (1.f / 16777216.f) + 1.0f);
}

// ---- exclusive prefix sum of cnt -> offs[0..N] ------------------------------
__global__ void k_scan(const int* __restrict__ cnt, int* __restrict__ offs, int N) {
    __shared__ int part[1024];
    int tid = threadIdx.x;
    int C = (N + 1023) / 1024;   // 16 for N=16384
    int base = tid * C;
    int loc[16];
    int sum = 0;
#pragma unroll
    for (int i = 0; i < 16; ++i) {
        if (i < C) {
            int idx = base + i;
            loc[i] = sum;
            sum += (idx < N) ? cnt[idx] : 0;
        }
    }
    part[tid] = sum;
    __syncthreads();
    for (int o = 1; o < 1024; o <<= 1) {
        int t = (tid >= o) ? part[tid - o] : 0;
        __syncthreads();
        part[tid] += t;
        __syncthreads();
    }
    int excl = part[tid] - sum;
#pragma unroll
    for (int i = 0; i < 16; ++i) {
        if (i < C) {
            int idx = base + i;
            if (idx < N) offs[idx] = excl + loc[i];
        }
    }
    if (tid == 1023) offs[N] = part[tid];
}

// ---- counting-sort edges into buckets, replicated cursors, packed record ----
__global__ void k_bucket(const int* __restrict__ ei, const float* __restrict__ ew,
                         const float* __restrict__ dis, const int* __restrict__ offs,
                         const int* __restrict__ off_rep, int* __restrict__ cursor_rep,
                         i2* __restrict__ barr, int N, int E) {
    int e = blockIdx.x * blockDim.x + threadIdx.x;
    if (e < E) {
        int rep = blockIdx.x & 7;
        int r = ntload(ei + e), c = ntload(ei + E + e);
        float norm = dis[r] * ntload(ew + e) * dis[c];
        size_t rc = (size_t)rep * N + c;
        int pos = offs[c] + off_rep[rc] + atomicAdd(&cursor_rep[rc], 1);
        i2 rec; rec.x = r; rec.y = __float_as_int(norm);
        __builtin_nontemporal_store(rec, barr + pos);
    }
}

// ---- per-row-pair gather (rows c0,c1 share one contiguous CSR range): -------
__global__ __launch_bounds__(256) void k_gather(const int* __restrict__ offs,
                         const i2* __restrict__ barr,
                         const float* __restrict__ xw, const unsigned short* __restrict__ xw16,
                         const float* __restrict__ dis,
                         const float* __restrict__ b1, float* __restrict__ h, int N) {
    int lane = threadIdx.x & 63;
    int sub = lane >> 4, q = lane & 15;
    int wid  = blockIdx.x * 4 + (threadIdx.x >> 6);
    int nw   = 4 * gridDim.x;
    const us4* xw16v = (const us4*)xw16;
    for (int cp = wid; cp < (N >> 1); cp += nw) {
        int c0 = 2 * cp, c1 = c0 + 1;
        int beg = ntload(offs + c0), mid = ntload(offs + c1), end = ntload(offs + c1 + 1);
        f4 A0 = {0.f, 0.f, 0.f, 0.f}, A1 = A0, B0 = A0, B1 = A0;
        for (int i = beg; i < end; i += 64) {
            int nloc = min(64, end - i);
            bool ok = (i + lane < end);
            i2 b = ok ? ntload(barr + i + lane) : (i2){0, 0};
            int   rv = b.x;
            float nv = __int_as_float(b.y);   // padded lanes: norm = 0
            int jmax = (nloc + 3) >> 2;
            int j = 0;
            for (; j + 4 <= jmax; j += 4) {   // 16 edges: 4 independent load chains
                int e0 = 4 * j + sub;
                int g0 = i + e0;
                int   r0 = __shfl(rv, e0),      r1 = __shfl(rv, e0 + 4);
                int   r2 = __shfl(rv, e0 + 8),  r3 = __shfl(rv, e0 + 12);
                float n0 = __shfl(nv, e0),      n1 = __shfl(nv, e0 + 4);
                float n2 = __shfl(nv, e0 + 8),  n3 = __shfl(nv, e0 + 12);
                us4 u0 = xw16v[(size_t)r0 * 16 + q];
                us4 u1 = xw16v[(size_t)r1 * 16 + q];
                us4 u2 = xw16v[(size_t)r2 * 16 + q];
                us4 u3 = xw16v[(size_t)r3 * 16 + q];
                float a0w = (g0      < mid) ? n0 : 0.f, b0w = n0 - a0w;
                float a1w = (g0 + 4  < mid) ? n1 : 0.f, b1w = n1 - a1w;
                float a2w = (g0 + 8  < mid) ? n2 : 0.f, b2w = n2 - a2w;
                float a3w = (g0 + 12 < mid) ? n3 : 0.f, b3w = n3 - a3w;
                A0.x = fmaf(bf2f(u0.x), a0w, A0.x); A0.y = fmaf(bf2f(u0.y), a0w, A0.y);
                A0.z = fmaf(bf2f(u0.z), a0w, A0.z); A0.w = fmaf(bf2f(u0.w), a0w, A0.w);
                B0.x = fmaf(bf2f(u0.x), b0w, B0.x); B0.y = fmaf(bf2f(u0.y), b0w, B0.y);
                B0.z = fmaf(bf2f(u0.z), b0w, B0.z); B0.w = fmaf(bf2f(u0.w), b0w, B0.w);
                A1.x = fmaf(bf2f(u1.x), a1w, A1.x); A1.y = fmaf(bf2f(u1.y), a1w, A1.y);
                A1.z = fmaf(bf2f(u1.z), a1w, A1.z); A1.w = fmaf(bf2f(u1.w), a1w, A1.w);
                B1.x = fmaf(bf2f(u1.x), b1w, B1.x); B1.y = fmaf(bf2f(u1.y), b1w, B1.y);
                B1.z = fmaf(bf2f(u1.z), b1w, B1.z); B1.w = fmaf(bf2f(u1.w), b1w, B1.w);
                A0.x = fmaf(bf2f(u2.x), a2w, A0.x); A0.y = fmaf(bf2f(u2.y), a2w, A0.y);
                A0.z = fmaf(bf2f(u2.z), a2w, A0.z); A0.w = fmaf(bf2f(u2.w), a2w, A0.w);
                B0.x = fmaf(bf2f(u2.x), b2w, B0.x); B0.y = fmaf(bf2f(u2.y), b2w, B0.y);
                B0.z = fmaf(bf2f(u2.z), b2w, B0.z); B0.w = fmaf(bf2f(u2.w), b2w, B0.w);
                A1.x = fmaf(bf2f(u3.x), a3w, A1.x); A1.y = fmaf(bf2f(u3.y), a3w, A1.y);
                A1.z = fmaf(bf2f(u3.z), a3w, A1.z); A1.w = fmaf(bf2f(u3.w), a3w, A1.w);
                B1.x = fmaf(bf2f(u3.x), b3w, B1.x); B1.y = fmaf(bf2f(u3.y), b3w, B1.y);
                B1.z = fmaf(bf2f(u3.z), b3w, B1.z); B1.w = fmaf(bf2f(u3.w), b3w, B1.w);
            }
            for (; j < jmax; ++j) {
                int e = 4 * j + sub;
                int g = i + e;
                int   r  = __shfl(rv, e);
                float nm = __shfl(nv, e);
                us4 u = xw16v[(size_t)r * 16 + q];
                float aw = (g < mid) ? nm : 0.f, bw = nm - aw;
                A0.x = fmaf(bf2f(u.x), aw, A0.x); A0.y = fmaf(bf2f(u.y), aw, A0.y);
                A0.z = fmaf(bf2f(u.z), aw, A0.z); A0.w = fmaf(bf2f(u.w), aw, A0.w);
                B0.x = fmaf(bf2f(u.x), bw, B0.x); B0.y = fmaf(bf2f(u.y), bw, B0.y);
                B0.z = fmaf(bf2f(u.z), bw, B0.z); B0.w = fmaf(bf2f(u.w), bw, B0.w);
            }
        }
        A0.x += A1.x; A0.y += A1.y; A0.z += A1.z; A0.w += A1.w;
        B0.x += B1.x; B0.y += B1.y; B0.z += B1.z; B0.w += B1.w;
        A0.x += __shfl_xor(A0.x, 16); A0.y += __shfl_xor(A0.y, 16);
        A0.z += __shfl_xor(A0.z, 16); A0.w += __shfl_xor(A0.w, 16);
        B0.x += __shfl_xor(B0.x, 16); B0.y += __shfl_xor(B0.y, 16);
        B0.z += __shfl_xor(B0.z, 16); B0.w += __shfl_xor(B0.w, 16);
        A0.x += __shfl_xor(A0.x, 32); A0.y += __shfl_xor(A0.y, 32);
        A0.z += __shfl_xor(A0.z, 32); A0.w += __shfl_xor(A0.w, 32);
        B0.x += __shfl_xor(B0.x, 32); B0.y += __shfl_xor(B0.y, 32);
        B0.z += __shfl_xor(B0.z, 32); B0.w += __shfl_xor(B0.w, 32);
        f4 bb = ((const f4*)b1)[q];
        f4 self0 = ntload((const f4*)xw + (size_t)c0 * 16 + q);
        f4 self1 = ntload((const f4*)xw + (size_t)c1 * 16 + q);
        float d0 = dis[c0], d1 = dis[c1];
        float dd0 = d0 * d0, dd1 = d1 * d1;
        f4 v0, v1;
        v0.x = A0.x + self0.x * dd0 + bb.x; v0.y = A0.y + self0.y * dd0 + bb.y;
        v0.z = A0.z + self0.z * dd0 + bb.z; v0.w = A0.w + self0.w * dd0 + bb.w;
        v1.x = B0.x + self1.x * dd1 + bb.x; v1.y = B0.y + self1.y * dd1 + bb.y;
        v1.z = B0.z + self1.z * dd1 + bb.z; v1.w = B0.w + self1.w * dd1 + bb.w;
        v0.x = v0.x > 0.f ? v0.x : 0.f; v0.y = v0.y > 0.f ? v0.y : 0.f;
        v0.z = v0.z > 0.f ? v0.z : 0.f; v0.w = v0.w > 0.f ? v0.w : 0.f;
        v1.x = v1.x > 0.f ? v1.x : 0.f; v1.y = v1.y > 0.f ? v1.y : 0.f;
        v1.z = v1.z > 0.f ? v1.z : 0.f; v1.w = v1.w > 0.f ? v1.w : 0.f;
        if (sub == 0) {
            __builtin_nontemporal_store(v0, (f4*)h + (size_t)c0 * 16 + q);
            __builtin_nontemporal_store(v1, (f4*)h + (size_t)c1 * 16 + q);
        }
    }
}

// ---- s = softmax((h@Wm1+bm1)@Wm2+bm2); emit f32 (output, NT) + bf16 copy ----
__global__ __launch_bounds__(256) void k_mlp(const float* __restrict__ h,
                      const float* __restrict__ Wm1, const float* __restrict__ bm1,
                      const float* __restrict__ Wm2, const float* __restrict__ bm2,
                      float* __restrict__ s, unsigned short* __restrict__ s16, int N) {
    __shared__ float w1l[4096], w2l[4096], b1l[64], b2l[64];
    __shared__ f4    ht[16][16];      // 4 KB
    __shared__ float tt[4][4][64];    // 4 KB per-wave layer-1 scratch
    for (int t = threadIdx.x; t < 4096; t += 256) {
        w1l[t] = Wm1[t];
        w2l[t] = Wm2[t];
    }
    if (threadIdx.x < 64) {
        b1l[threadIdx.x] = bm1[threadIdx.x];
        b2l[threadIdx.x] = bm2[threadIdx.x];
    }
    int lane = threadIdx.x & 63;
    int wv   = threadIdx.x >> 6;
    for (int base = blockIdx.x * 16; base < N; base += gridDim.x * 16) {
        __syncthreads();
        for (int t = threadIdx.x; t < 16 * 16; t += 256)
            ((f4*)ht)[t] = ntload((const f4*)h + (size_t)base * 16 + t);
        __syncthreads();
        int r0 = wv * 4;
        float t0 = b1l[lane], t1 = t0, t2 = t0, t3 = t0;
#pragma unroll
        for (int q = 0; q < 16; ++q) {
            f4 h0 = ht[r0][q], h1 = ht[r0 + 1][q], h2 = ht[r0 + 2][q], h3 = ht[r0 + 3][q];
            float wa = w1l[(4 * q + 0) * 64 + lane];
            float wb = w1l[(4 * q + 1) * 64 + lane];
            float wc = w1l[(4 * q + 2) * 64 + lane];
            float wd = w1l[(4 * q + 3) * 64 + lane];
            t0 = fmaf(h0.x, wa, t0); t0 = fmaf(h0.y, wb, t0); t0 = fmaf(h0.z, wc, t0); t0 = fmaf(h0.w, wd, t0);
            t1 = fmaf(h1.x, wa, t1); t1 = fmaf(h1.y, wb, t1); t1 = fmaf(h1.z, wc, t1); t1 = fmaf(h1.w, wd, t1);
            t2 = fmaf(h2.x, wa, t2); t2 = fmaf(h2.y, wb, t2); t2 = fmaf(h2.z, wc, t2); t2 = fmaf(h2.w, wd, t2);
            t3 = fmaf(h3.x, wa, t3); t3 = fmaf(h3.y, wb, t3); t3 = fmaf(h3.z, wc, t3); t3 = fmaf(h3.w, wd, t3);
        }
        tt[wv][0][lane] = t0; tt[wv][1][lane] = t1;
        tt[wv][2][lane] = t2; tt[wv][3][lane] = t3;
        __syncthreads();
        float g0 = b2l[lane], g1 = g0, g2 = g0, g3 = g0;
#pragma unroll
        for (int q = 0; q < 16; ++q) {
            f4 u0 = ((f4*)tt[wv][0])[q], u1 = ((f4*)tt[wv][1])[q];
            f4 u2 = ((f4*)tt[wv][2])[q], u3 = ((f4*)tt[wv][3])[q];
            float wa = w2l[(4 * q + 0) * 64 + lane];
            float wb = w2l[(4 * q + 1) * 64 + lane];
            float wc = w2l[(4 * q + 2) * 64 + lane];
            float wd = w2l[(4 * q + 3) * 64 + lane];
            g0 = fmaf(u0.x, wa, g0); g0 = fmaf(u0.y, wb, g0); g0 = fmaf(u0.z, wc, g0); g0 = fmaf(u0.w, wd, g0);
            g1 = fmaf(u1.x, wa, g1); g1 = fmaf(u1.y, wb, g1); g1 = fmaf(u1.z, wc, g1); g1 = fmaf(u1.w, wd, g1);
            g2 = fmaf(u2.x, wa, g2); g2 = fmaf(u2.y, wb, g2); g2 = fmaf(u2.z, wc, g2); g2 = fmaf(u2.w, wd, g2);
            g3 = fmaf(u3.x, wa, g3); g3 = fmaf(u3.y, wb, g3); g3 = fmaf(u3.z, wc, g3); g3 = fmaf(u3.w, wd, g3);
        }
        float m0 = g0, m1 = g1, m2 = g2, m3 = g3;
#pragma unroll
        for (int o = 32; o > 0; o >>= 1) {
            m0 = fmaxf(m0, __shfl_xor(m0, o));
            m1 = fmaxf(m1, __shfl_xor(m1, o));
            m2 = fmaxf(m2, __shfl_xor(m2, o));
            m3 = fmaxf(m3, __shfl_xor(m3, o));
        }
        float e0 = __expf(g0 - m0), e1 = __expf(g1 - m1);
        float e2 = __expf(g2 - m2), e3 = __expf(g3 - m3);
        float s0 = e0, s1 = e1, s2 = e2, s3 = e3;
#pragma unroll
        for (int o = 32; o > 0; o >>= 1) {
            s0 += __shfl_xor(s0, o);
            s1 += __shfl_xor(s1, o);
            s2 += __shfl_xor(s2, o);
            s3 += __shfl_xor(s3, o);
        }
        int gr = base + r0;
        float o0 = e0 / s0, o1 = e1 / s1, o2 = e2 / s2, o3 = e3 / s3;
        __builtin_nontemporal_store(o0, s + (size_t)(gr + 0) * 64 + lane);
        __builtin_nontemporal_store(o1, s + (size_t)(gr + 1) * 64 + lane);
        __builtin_nontemporal_store(o2, s + (size_t)(gr + 2) * 64 + lane);
        __builtin_nontemporal_store(o3, s + (size_t)(gr + 3) * 64 + lane);
        s16[(size_t)(gr + 0) * 64 + lane] = f2bf(o0);
        s16[(size_t)(gr + 1) * 64 + lane] = f2bf(o1);
        s16[(size_t)(gr + 2) * 64 + lane] = f2bf(o2);
        s16[(size_t)(gr + 3) * 64 + lane] = f2bf(o3);
    }
}

// ---- FAT kernel B: blocks [0,2048): trace; [2048,2304): row reductions ------
__global__ __launch_bounds__(256) void k_rt(const int* __restrict__ offs,
                         const i2* __restrict__ barr,
                         const unsigned short* __restrict__ s16,
                         const float* __restrict__ s, const int* __restrict__ cnt,
                         float* __restrict__ ssg, float* __restrict__ cag,
                         float* __restrict__ csg, float* __restrict__ tracearr, int N) {
    __shared__ float tile[64][64];   // 16 KB (rowred branch)
    __shared__ float bsum;
    int lane = threadIdx.x & 63;
    int wv   = threadIdx.x >> 6;
    if (blockIdx.x >= 2048) {
        // ---- rowred branch: 256 blocks, one 64-row tile each ----
        int base = (blockIdx.x - 2048) * 64;
        if (base >= N) return;
        for (int t = threadIdx.x; t < 1024; t += 256)
            ((f4*)tile)[t] = ntload((const f4*)(s + (size_t)base * 64) + t);
        __syncthreads();
        float acc[16];
#pragma unroll
        for (int i = 0; i < 16; ++i) acc[i] = 0.f;
        for (int r = 0; r < 64; ++r) {
            float sj = tile[r][lane];
            const float* brow = &tile[r][wv * 16];
#pragma unroll
            for (int i = 0; i < 16; ++i) acc[i] = fmaf(brow[i], sj, acc[i]);
        }
        float csj = 0.f, caj = 0.f;
#pragma unroll
        for (int i = 0; i < 16; ++i) {
            int r = wv * 16 + i;
            float sj = tile[r][lane];
            csj += sj;
            caj = fmaf(sj, (float)cnt[base + r], caj);
        }
#pragma unroll
        for (int i = 0; i < 16; ++i) atomicAdd(&ssg[(wv * 16 + i) * 64 + lane], acc[i]);
        atomicAdd(&csg[lane], csj);
        atomicAdd(&cag[lane], caj);
        return;
    }
    // ---- trace branch: 2048 blocks, row-pairs over contiguous CSR ranges ----
    int sub = lane >> 4, q = lane & 15;
    int wid  = blockIdx.x * 4 + wv;
    int nw   = 4 * 2048;
    const us4* s16v = (const us4*)s16;
    float tacc = 0.f;
    for (int cp = wid; cp < (N >> 1); cp += nw) {
        int c0 = 2 * cp, c1 = c0 + 1;
        int beg = ntload(offs + c0), mid = ntload(offs + c1), end = ntload(offs + c1 + 1);
        us4 scu0 = s16v[(size_t)c0 * 16 + q];
        us4 scu1 = s16v[(size_t)c1 * 16 + q];
        f4 sc0 = {bf2f(scu0.x), bf2f(scu0.y), bf2f(scu0.z), bf2f(scu0.w)};
        f4 sc1 = {bf2f(scu1.x), bf2f(scu1.y), bf2f(scu1.z), bf2f(scu1.w)};
        f4 A0 = {0.f, 0.f, 0.f, 0.f}, A1 = A0, B0 = A0, B1 = A0;
        for (int i = beg; i < end; i += 64) {
            int nloc = min(64, end - i);
            int rv = (i + lane < end) ? ntload(barr + i + lane).x : 0;
            int jmax = (nloc + 3) >> 2;
            int j = 0;
            for (; j + 4 <= jmax; j += 4) {
                int e0 = 4 * j + sub;
                int g0 = i + e0;
                int r0 = __shfl(rv, e0),     r1 = __shfl(rv, e0 + 4);
                int r2 = __shfl(rv, e0 + 8), r3 = __shfl(rv, e0 + 12);
                float n0 = (e0      < nloc) ? 1.f : 0.f;
                float n1 = (e0 + 4  < nloc) ? 1.f : 0.f;
                float n2 = (e0 + 8  < nloc) ? 1.f : 0.f;
                float n3 = (e0 + 12 < nloc) ? 1.f : 0.f;
                us4 u0 = s16v[(size_t)r0 * 16 + q];
                us4 u1 = s16v[(size_t)r1 * 16 + q];
                us4 u2 = s16v[(size_t)r2 * 16 + q];
                us4 u3 = s16v[(size_t)r3 * 16 + q];
                float a0w = (g0      < mid) ? n0 : 0.f, b0w = n0 - a0w;
                float a1w = (g0 + 4  < mid) ? n1 : 0.f, b1w = n1 - a1w;
                float a2w = (g0 + 8  < mid) ? n2 : 0.f, b2w = n2 - a2w;
                float a3w = (g0 + 12 < mid) ? n3 : 0.f, b3w = n3 - a3w;
                A0.x = fmaf(bf2f(u0.x), a0w, A0.x); A0.y = fmaf(bf2f(u0.y), a0w, A0.y);
                A0.z = fmaf(bf2f(u0.z), a0w, A0.z); A0.w = fmaf(bf2f(u0.w), a0w, A0.w);
                B0.x = fmaf(bf2f(u0.x), b0w, B0.x); B0.y = fmaf(bf2f(u0.y), b0w, B0.y);
                B0.z = fmaf(bf2f(u0.z), b0w, B0.z); B0.w = fmaf(bf2f(u0.w), b0w, B0.w);
                A1.x = fmaf(bf2f(u1.x), a1w, A1.x); A1.y = fmaf(bf2f(u1.y), a1w, A1.y);
                A1.z = fmaf(bf2f(u1.z), a1w, A1.z); A1.w = fmaf(bf2f(u1.w), a1w, A1.w);
                B1.x = fmaf(bf2f(u1.x), b1w, B1.x); B1.y = fmaf(bf2f(u1.y), b1w, B1.y);
                B1.z = fmaf(bf2f(u1.z), b1w, B1.z); B1.w = fmaf(bf2f(u1.w), b1w, B1.w);
                A0.x = fmaf(bf2f(u2.x), a2w, A0.x); A0.y = fmaf(bf2f(u2.y), a2w, A0.y);
                A0.z = fmaf(bf2f(u2.z), a2w, A0.z); A0.w = fmaf(bf2f(u2.w), a2w, A0.w);
                B0.x = fmaf(bf2f(u2.x), b2w, B0.x); B0.y = fmaf(bf2f(u2.y), b2w, B0.y);
                B0.z = fmaf(bf2f(u2.z), b2w, B0.z); B0.w = fmaf(bf2f(u2.w), b2w, B0.w);
                A1.x = fmaf(bf2f(u3.x), a3w, A1.x); A1.y = fmaf(bf2f(u3.y), a3w, A1.y);
                A1.z = fmaf(bf2f(u3.z), a3w, A1.z); A1.w = fmaf(bf2f(u3.w), a3w, A1.w);
                B1.x = fmaf(bf2f(u3.x), b3w, B1.x); B1.y = fmaf(bf2f(u3.y), b3w, B1.y);
                B1.z = fmaf(bf2f(u3.z), b3w, B1.z); B1.w = fmaf(bf2f(u3.w), b3w, B1.w);
            }
            for (; j < jmax; ++j) {
                int e = 4 * j + sub;
                int g = i + e;
                int r = __shfl(rv, e);
                float m = (e < nloc) ? 1.f : 0.f;
                us4 u = s16v[(size_t)r * 16 + q];
                float aw = (g < mid) ? m : 0.f, bw = m - aw;
                A0.x = fmaf(bf2f(u.x), aw, A0.x); A0.y = fmaf(bf2f(u.y), aw, A0.y);
                A0.z = fmaf(bf2f(u.z), aw, A0.z); A0.w = fmaf(bf2f(u.w), aw, A0.w);
                B0.x = fmaf(bf2f(u.x), bw, B0.x); B0.y = fmaf(bf2f(u.y), bw, B0.y);
                B0.z = fmaf(bf2f(u.z), bw, B0.z); B0.w = fmaf(bf2f(u.w), bw, B0.w);
            }
        }
        A0.x += A1.x; A0.y += A1.y; A0.z += A1.z; A0.w += A1.w;
        B0.x += B1.x; B0.y += B1.y; B0.z += B1.z; B0.w += B1.w;
        A0.x += __shfl_xor(A0.x, 16); A0.y += __shfl_xor(A0.y, 16);
        A0.z += __shfl_xor(A0.z, 16); A0.w += __shfl_xor(A0.w, 16);
        B0.x += __shfl_xor(B0.x, 16); B0.y += __shfl_xor(B0.y, 16);
        B0.z += __shfl_xor(B0.z, 16); B0.w += __shfl_xor(B0.w, 16);
        A0.x += __shfl_xor(A0.x, 32); A0.y += __shfl_xor(A0.y, 32);
        A0.z += __shfl_xor(A0.z, 32); A0.w += __shfl_xor(A0.w, 32);
        B0.x += __shfl_xor(B0.x, 32); B0.y += __shfl_xor(B0.y, 32);
        B0.z += __shfl_xor(B0.z, 32); B0.w += __shfl_xor(B0.w, 32);
        tacc += A0.x * sc0.x + A0.y * sc0.y + A0.z * sc0.z + A0.w * sc0.w;
        tacc += B0.x * sc1.x + B0.y * sc1.y + B0.z * sc1.z + B0.w * sc1.w;
    }
    tacc *= 0.25f;   // each q-partial replicated across 4 subs
#pragma unroll
    for (int o = 32; o > 0; o >>= 1) tacc += __shfl_xor(tacc, o);
    if (threadIdx.x == 0) bsum = 0.f;
    __syncthreads();
    if (lane == 0) atomicAdd(&bsum, tacc);
    __syncthreads();
    if (threadIdx.x == 0) tracearr[blockIdx.x] = bsum;   // per-block partial
}

// ---- finalize: spectral + ortho + cluster loss ------------------------------
__global__ void k_final(const float* __restrict__ ssg, const float* __restrict__ cag,
                        const float* __restrict__ csg, const float* __restrict__ tracearr,
                        int ntr, float Ef, float Nf, float* __restrict__ out) {
    __shared__ float red[256];
    int tid = threadIdx.x;

    float a = 0.f;
    for (int t = tid; t < ntr; t += 256) a += tracearr[t];
    red[tid] = a; __syncthreads();
    for (int o = 128; o > 0; o >>= 1) { if (tid < o) red[tid] += red[tid + o]; __syncthreads(); }
    float trace = red[0]; __syncthreads();

    a = 0.f;
    for (int t = tid; t < 4096; t += 256) { float v = ssg[t]; a += v * v; }
    red[tid] = a; __syncthreads();
    for (int o = 128; o > 0; o >>= 1) { if (tid < o) red[tid] += red[tid + o]; __syncthreads(); }
    float ss_sumsq = red[0]; __syncthreads();

    a = (tid < 64) ? ssg[tid * 64 + tid] : 0.f;
    red[tid] = a; __syncthreads();
    for (int o = 128; o > 0; o >>= 1) { if (tid < o) red[tid] += red[tid + o]; __syncthreads(); }
    float tr_ss = red[0]; __syncthreads();

    a = (tid < 64) ? cag[tid] * cag[tid] : 0.f;
    red[tid] = a; __syncthreads();
    for (int o = 128; o > 0; o >>= 1) { if (tid < o) red[tid] += red[tid + o]; __syncthreads(); }
    float ca_ss = red[0]; __syncthreads();

    a = (tid < 64) ? csg[tid] * csg[tid] : 0.f;
    red[tid] = a; __syncthreads();
    for (int o = 128; o > 0; o >>= 1) { if (tid < o) red[tid] += red[tid + o]; __syncthreads(); }
    float cs_ss = red[0];

    if (tid == 0) {
        // 2m = deg.sum() = E
        float spec = -(trace - ca_ss / Ef) / Ef;
        float ss_fro = sqrtf(ss_sumsq);
        // ||ss/fro - I/8||_F^2 = 1 - tr(ss)/(4*fro) + 1
        float ortho = sqrtf(fmaxf(2.f - tr_ss / (4.f * ss_fro), 0.f));
        float clus = sqrtf(cs_ss) / Nf * 8.f - 1.f;
        out[0] = spec + ortho + clus;
    }
}

extern "C" void kernel_launch(void* const* d_in, const int* in_sizes, int n_in,
                              void* d_out, int out_size, void* d_ws, size_t ws_size,
                              hipStream_t stream) {
    const float* x   = (const float*)d_in[0];
    const int*   ei  = (const int*)d_in[1];
    const float* ew  = (const float*)d_in[2];
    const float* W1  = (const float*)d_in[3];
    const float* b1  = (const float*)d_in[4];
    const float* Wm1 = (const float*)d_in[5];
    const float* bm1 = (const float*)d_in[6];
    const float* Wm2 = (const float*)d_in[7];
    const float* bm2 = (const float*)d_in[8];
    float* out = (float*)d_out;

    const int N = in_sizes[0] / 128;   // 16384
    const int E = in_sizes[2];         // 524288
    const int TGRID = 2304;            // fat kernel B grid (2048 trace + 256 rowred)

    char* base = (char*)d_ws;
    // --- zeroed region (atomics accumulate) ---
    unsigned long long* deg_rep = (unsigned long long*)base;        // 8N u64 (1 MB)
    int*   cursor_rep = (int*)(base + (size_t)64 * N);              // 8N int (512 KB)
    float* ssg = (float*)(base + (size_t)96 * N);                   // 4096 f
    float* cag = ssg + 4096;                                        // 64
    float* csg = cag + 64;                                          // 64
    size_t zbytes = (size_t)96 * N + (4096 + 128) * 4;
    // --- uninitialized region ---
    char* up = base + ((zbytes + 15) & ~(size_t)15);
    int*   cnt = (int*)up;            up += (size_t)4 * N;
    float* dis = (float*)up;          up += (size_t)4 * N;
    int*   offs = (int*)up;           up += (size_t)4 * (N + 1);
    float* tracearr = (float*)up;     up += (size_t)4 * TGRID;
    up = (char*)(((size_t)up + 15) & ~(size_t)15);
    float* xw = (float*)up;           up += (size_t)4 * N * 64;     // 4 MB
    float* h  = (float*)up;           up += (size_t)4 * N * 64;     // 4 MB
    int*   off_rep = (int*)h;         // aliases h: written k_red, read k_bucket, dead before k_gather writes h
    i2*    barr = (i2*)up;            up += (size_t)8 * E;          // 4 MB
    unsigned short* xw16 = (unsigned short*)up; up += (size_t)2 * N * 64;  // 2 MB
    unsigned short* s16  = (unsigned short*)up;                            // 2 MB
    float* sbuf = out;                // s lives in d_out (f32 output 0)

    hipMemsetAsync(d_ws, 0, zbytes, stream);

    k_degxw<<<2560, 256, 0, stream>>>(ei, ew, deg_rep, x, W1, xw, xw16, N, E);
    k_red<<<(N + 255) / 256, 256, 0, stream>>>(deg_rep, off_rep, cnt, dis, N);
    k_scan<<<1, 1024, 0, stream>>>(cnt, offs, N);
    k_bucket<<<(E + 255) / 256, 256, 0, stream>>>(ei, ew, dis, offs, off_rep, cursor_rep, barr, N, E);
    k_gather<<<2048, 256, 0, stream>>>(offs, barr, xw, xw16, dis, b1, h, N);
    k_mlp<<<512, 256, 0, stream>>>(h, Wm1, bm1, Wm2, bm2, sbuf, s16, N);
    k_rt<<<TGRID, 256, 0, stream>>>(offs, barr, s16, sbuf, cnt, ssg, cag, csg, tracearr, N);
    k_final<<<1, 256, 0, stream>>>(ssg, cag, csg, tracearr, TGRID, (float)E, (float)N,
                                   out + (size_t)N * 64);
}